// Round 6
// baseline (582.844 us; speedup 1.0000x reference)
//
#include <hip/hip_runtime.h>
#include <hip/hip_bf16.h>
#include <math.h>

// 3-layer GCN on MI355X.
// R5: (a) build = single atomic pass (count+scatter merged, rank buffer gone);
//     (b) agg fused with the NEXT layer's GEMM (wave shuffle-matmul, W in LDS)
//         -> fp32 `out` round-trip eliminated for layers 1,2; dispatches 10->6;
//     (c) dinv computed inline from cnt (kernel+buffer dropped).
//     hs staged in bf16 (pre-scaled by dinv[row]); fp32 accumulation throughout.

#define FDIM 64

// ---------- adjacency build: one atomic pass ----------
// adjF[c*cap + rank] = row ; cnt[c] = in-degree. rank>=cap handled by slow path.
__global__ void build_kernel(const int* __restrict__ row, const int* __restrict__ col,
                             int* __restrict__ cnt, int* __restrict__ adjF,
                             int e, int cap) {
    int i = blockIdx.x * blockDim.x + threadIdx.x;
    if (i < e) {
        int c = col[i];
        int r = atomicAdd(&cnt[c], 1);
        if (r < cap) adjF[(size_t)c * cap + r] = row[i];
    }
}

// ---------- layer 1 GEMM: Hs[n,64] = bf16( rsqrt(deg+1) * (X @ W) ) ----------
__global__ __launch_bounds__(256) void gemm_kernel(const float* __restrict__ X,
                                                   const float* __restrict__ W,
                                                   const int* __restrict__ cnt,
                                                   __hip_bfloat16* __restrict__ Hout, int n) {
    __shared__ float Ws[64][64];
    __shared__ float Xs[64][64];
    const int t = threadIdx.x;
    const int row0 = blockIdx.x * 64;
    #pragma unroll
    for (int i = t; i < 4096; i += 256) Ws[i >> 6][i & 63] = W[i];
    #pragma unroll
    for (int i = t; i < 4096; i += 256) {
        int r = i >> 6, c = i & 63;
        int gr = row0 + r;
        Xs[r][c] = (gr < n) ? X[(size_t)gr * FDIM + c] : 0.0f;
    }
    __syncthreads();
    const int j = t & 63;
    const int ng = t >> 6;
    float acc[16];
    #pragma unroll
    for (int r = 0; r < 16; r++) acc[r] = 0.0f;
    for (int k = 0; k < 64; k++) {
        float w = Ws[k][j];
        #pragma unroll
        for (int r = 0; r < 16; r++)
            acc[r] += Xs[ng * 16 + r][k] * w;
    }
    #pragma unroll
    for (int r = 0; r < 16; r++) {
        int gr = row0 + ng * 16 + r;
        if (gr < n) {
            float dv = rsqrtf((float)cnt[gr] + 1.0f);
            Hout[(size_t)gr * FDIM + j] = __float2bfloat16(acc[r] * dv);
        }
    }
}

// ---------- shared gather: sum of pre-scaled neighbor rows (+ self) ----------
// Returns per-lane float2 of features (2*(lane&31), 2*(lane&31)+1); valid in ALL lanes.
__device__ __forceinline__ float2 gather_sum(const __hip_bfloat162* __restrict__ hs2,
                                             const int* __restrict__ adjF,
                                             int v, int deg, int cap, int lane,
                                             const int* __restrict__ erow,
                                             const int* __restrict__ ecol, int etot) {
    const int f2 = lane & 31;
    const int half = lane >> 5;
    float2 a0 = {0.f,0.f}, a1 = {0.f,0.f}, a2 = {0.f,0.f}, a3 = {0.f,0.f};
    float2 a4 = {0.f,0.f}, a5 = {0.f,0.f}, a6 = {0.f,0.f}, a7 = {0.f,0.f};

    if (half == 0) {                       // self loop once
        __hip_bfloat162 sv = hs2[(size_t)v * 32 + f2];
        a0.x = __bfloat162float(sv.x);
        a0.y = __bfloat162float(sv.y);
    }

    if (deg <= cap) {
        const int* __restrict__ av = adjF + (size_t)v * cap;
        for (int base = 0; base < deg; base += 64) {
            int m = deg - base; if (m > 64) m = 64;
            int uvec = 0;
            if (lane < m) uvec = av[base + lane];
            const int pairs = m >> 1;
            int k = 0;
            for (; k + 8 <= pairs; k += 8) {
                int u0 = __shfl(uvec, 2*(k+0) + half, 64);
                int u1 = __shfl(uvec, 2*(k+1) + half, 64);
                int u2 = __shfl(uvec, 2*(k+2) + half, 64);
                int u3 = __shfl(uvec, 2*(k+3) + half, 64);
                int u4 = __shfl(uvec, 2*(k+4) + half, 64);
                int u5 = __shfl(uvec, 2*(k+5) + half, 64);
                int u6 = __shfl(uvec, 2*(k+6) + half, 64);
                int u7 = __shfl(uvec, 2*(k+7) + half, 64);
                __hip_bfloat162 b0 = hs2[(size_t)u0 * 32 + f2];
                __hip_bfloat162 b1 = hs2[(size_t)u1 * 32 + f2];
                __hip_bfloat162 b2 = hs2[(size_t)u2 * 32 + f2];
                __hip_bfloat162 b3 = hs2[(size_t)u3 * 32 + f2];
                __hip_bfloat162 b4 = hs2[(size_t)u4 * 32 + f2];
                __hip_bfloat162 b5 = hs2[(size_t)u5 * 32 + f2];
                __hip_bfloat162 b6 = hs2[(size_t)u6 * 32 + f2];
                __hip_bfloat162 b7 = hs2[(size_t)u7 * 32 + f2];
                a0.x += __bfloat162float(b0.x); a0.y += __bfloat162float(b0.y);
                a1.x += __bfloat162float(b1.x); a1.y += __bfloat162float(b1.y);
                a2.x += __bfloat162float(b2.x); a2.y += __bfloat162float(b2.y);
                a3.x += __bfloat162float(b3.x); a3.y += __bfloat162float(b3.y);
                a4.x += __bfloat162float(b4.x); a4.y += __bfloat162float(b4.y);
                a5.x += __bfloat162float(b5.x); a5.y += __bfloat162float(b5.y);
                a6.x += __bfloat162float(b6.x); a6.y += __bfloat162float(b6.y);
                a7.x += __bfloat162float(b7.x); a7.y += __bfloat162float(b7.y);
            }
            for (; k < pairs; k++) {
                int u = __shfl(uvec, 2*k + half, 64);
                __hip_bfloat162 b = hs2[(size_t)u * 32 + f2];
                a0.x += __bfloat162float(b.x); a0.y += __bfloat162float(b.y);
            }
            if (m & 1) {
                int u = __shfl(uvec, m - 1, 64);
                if (half == 0) {
                    __hip_bfloat162 b = hs2[(size_t)u * 32 + f2];
                    a1.x += __bfloat162float(b.x); a1.y += __bfloat162float(b.y);
                }
            }
        }
    } else {
        // deg > cap (prob ~0): wave-cooperative scan of the raw edge list
        for (int base = 0; base < etot; base += 64) {
            int m = etot - base; if (m > 64) m = 64;
            int c = -1, r = 0;
            if (lane < m) { c = ecol[base + lane]; r = erow[base + lane]; }
            unsigned long long mask = __ballot(c == v);
            while (mask) {
                int j = __ffsll((long long)mask) - 1;
                mask &= mask - 1;
                int u = __shfl(r, j, 64);
                if (half == 0) {
                    __hip_bfloat162 b = hs2[(size_t)u * 32 + f2];
                    a0.x += __bfloat162float(b.x); a0.y += __bfloat162float(b.y);
                }
            }
        }
    }

    float2 tot;
    tot.x = ((a0.x + a1.x) + (a2.x + a3.x)) + ((a4.x + a5.x) + (a6.x + a7.x));
    tot.y = ((a0.y + a1.y) + (a2.y + a3.y)) + ((a4.y + a5.y) + (a6.y + a7.y));
    tot.x += __shfl_xor(tot.x, 32, 64);    // both halves now hold full sums
    tot.y += __shfl_xor(tot.y, 32, 64);
    return tot;
}

// ---------- fused: agg (+bias,ELU) then z @ Wn, pre-scaled, bf16 out ----------
__global__ __launch_bounds__(256) void agg_mm_kernel(const __hip_bfloat16* __restrict__ hs,
                                                     const int* __restrict__ adjF,
                                                     const int* __restrict__ cnt,
                                                     const float* __restrict__ bias,
                                                     const float* __restrict__ Wn,
                                                     __hip_bfloat16* __restrict__ hs_out,
                                                     int n, int cap,
                                                     const int* __restrict__ erow,
                                                     const int* __restrict__ ecol, int etot) {
    __shared__ float Ws[64][64];           // next layer's W
    const int t = threadIdx.x;
    #pragma unroll
    for (int i = t; i < 4096; i += 256) Ws[i >> 6][i & 63] = Wn[i];
    __syncthreads();                        // only barrier; before any divergence

    const int v = blockIdx.x * 4 + (t >> 6);
    const int lane = t & 63;
    const int f2 = lane & 31;
    const bool active = v < n;

    float2 tot = {0.f, 0.f};
    float dv = 0.0f;
    if (active) {
        const int deg = cnt[v];
        dv = rsqrtf((float)deg + 1.0f);
        tot = gather_sum((const __hip_bfloat162*)hs, adjF, v, deg, cap, lane,
                         erow, ecol, etot);
    }

    // bias + ELU (features 2*f2, 2*f2+1; replicated in both halves)
    float2 bv = ((const float2*)bias)[f2];
    float zx = tot.x * dv + bv.x;
    float zy = tot.y * dv + bv.y;
    zx = (zx > 0.0f) ? zx : (__expf(zx) - 1.0f);
    zy = (zy > 0.0f) ? zy : (__expf(zy) - 1.0f);

    // wave matmul: lane j -> acc = sum_k z_k * Ws[k][j]
    float acc = 0.0f;
    #pragma unroll
    for (int m = 0; m < 32; m++) {
        float rx = __shfl(zx, m, 64);       // feature 2m (readlane)
        float ry = __shfl(zy, m, 64);       // feature 2m+1
        acc += rx * Ws[2*m][lane] + ry * Ws[2*m+1][lane];
    }
    if (active)
        hs_out[(size_t)v * FDIM + lane] = __float2bfloat16(acc * dv);
}

// ---------- final layer: agg + bias, fp32 out, no ELU ----------
__global__ __launch_bounds__(256) void agg_final_kernel(const __hip_bfloat16* __restrict__ hs,
                                                        const int* __restrict__ adjF,
                                                        const int* __restrict__ cnt,
                                                        const float* __restrict__ bias,
                                                        float* __restrict__ out,
                                                        int n, int cap,
                                                        const int* __restrict__ erow,
                                                        const int* __restrict__ ecol, int etot) {
    const int v = blockIdx.x * 4 + (threadIdx.x >> 6);
    const int lane = threadIdx.x & 63;
    if (v >= n) return;
    const int f2 = lane & 31;
    const int deg = cnt[v];
    const float dv = rsqrtf((float)deg + 1.0f);
    float2 tot = gather_sum((const __hip_bfloat162*)hs, adjF, v, deg, cap, lane,
                            erow, ecol, etot);
    if ((lane >> 5) == 0) {
        float2 bv = ((const float2*)bias)[f2];
        float rx = tot.x * dv + bv.x;
        float ry = tot.y * dv + bv.y;
        ((float2*)out)[(size_t)v * 32 + f2] = make_float2(rx, ry);
    }
}

// ---------- launch ----------

extern "C" void kernel_launch(void* const* d_in, const int* in_sizes, int n_in,
                              void* d_out, int out_size, void* d_ws, size_t ws_size,
                              hipStream_t stream) {
    const float* x   = (const float*)d_in[0];
    const int*   ei  = (const int*)d_in[1];
    const float* W1  = (const float*)d_in[2];
    const float* b1  = (const float*)d_in[3];
    const float* W2  = (const float*)d_in[4];
    const float* b2  = (const float*)d_in[5];
    const float* W3  = (const float*)d_in[6];
    const float* b3  = (const float*)d_in[7];

    const int N = in_sizes[0] / FDIM;      // 100000
    const int E = in_sizes[1] / 2;         // 1600000
    const int* erow = ei;                   // sources
    const int* ecol = ei + E;               // targets

    char* p = (char*)d_ws;
    __hip_bfloat16* hsA = (__hip_bfloat16*)p;  p += (size_t)N * FDIM * sizeof(__hip_bfloat16);
    __hip_bfloat16* hsB = (__hip_bfloat16*)p;  p += (size_t)N * FDIM * sizeof(__hip_bfloat16);
    int* cnt  = (int*)p;  p += (size_t)N * sizeof(int);
    int* adjF = (int*)p;

    // adjacency capacity: biggest of {64,48,32} that fits the workspace
    size_t used = (size_t)(p - (char*)d_ws);
    int cap = 64;
    while (cap > 32 && used + (size_t)N * cap * sizeof(int) > ws_size) cap -= 16;

    float* outb = (float*)d_out;

    const int TB = 256;
    const int nblkE = (E + TB - 1) / TB;
    const int nblkG = (N + 63) / 64;
    const int nblkA = (N + 3) / 4;

    hipMemsetAsync(cnt, 0, (size_t)N * sizeof(int), stream);
    build_kernel<<<nblkE, TB, 0, stream>>>(erow, ecol, cnt, adjF, E, cap);

    gemm_kernel<<<nblkG, TB, 0, stream>>>(x, W1, cnt, hsA, N);
    agg_mm_kernel<<<nblkA, TB, 0, stream>>>(hsA, adjF, cnt, b1, W2, hsB, N, cap, erow, ecol, E);
    agg_mm_kernel<<<nblkA, TB, 0, stream>>>(hsB, adjF, cnt, b2, W3, hsA, N, cap, erow, ecol, E);
    agg_final_kernel<<<nblkA, TB, 0, stream>>>(hsA, adjF, cnt, b3, outb, N, cap, erow, ecol, E);
}

// Round 7
// 491.690 us; speedup vs baseline: 1.1854x; 1.1854x over previous
//
#include <hip/hip_runtime.h>
#include <hip/hip_bf16.h>
#include <math.h>

// 3-layer GCN on MI355X.
// R6: revert R5's wave-fused matmul (VALU-bound: 145us vs 55+12 split).
//     Keep: single-atomic-pass build (count+scatter merged), inline dinv,
//     bf16 hs staging. NEW: inter-layer z also staged bf16 (agg writes bf16,
//     gemm2/3 read bf16) -> same 51MB round-trip saving as the fusion,
//     without the per-wave matmul cost. fp32 accumulation everywhere.

#define FDIM 64

// ---------- adjacency build: one atomic pass ----------
// adjF[c*cap + rank] = row ; cnt[c] = in-degree. rank>=cap handled by slow path.
__global__ void build_kernel(const int* __restrict__ row, const int* __restrict__ col,
                             int* __restrict__ cnt, int* __restrict__ adjF,
                             int e, int cap) {
    int i = blockIdx.x * blockDim.x + threadIdx.x;
    if (i < e) {
        int c = col[i];
        int r = atomicAdd(&cnt[c], 1);
        if (r < cap) adjF[(size_t)c * cap + r] = row[i];
    }
}

// ---------- layer-1 GEMM: Hs = bf16( rsqrt(deg+1) * (X_f32 @ W) ) ----------
__global__ __launch_bounds__(256) void gemm_f32_kernel(const float* __restrict__ X,
                                                       const float* __restrict__ W,
                                                       const int* __restrict__ cnt,
                                                       __hip_bfloat16* __restrict__ Hout, int n) {
    __shared__ float Ws[64][64];
    __shared__ float Xs[64][64];
    const int t = threadIdx.x;
    const int row0 = blockIdx.x * 64;
    #pragma unroll
    for (int i = t; i < 4096; i += 256) Ws[i >> 6][i & 63] = W[i];
    #pragma unroll
    for (int i = t; i < 4096; i += 256) {
        int r = i >> 6, c = i & 63;
        int gr = row0 + r;
        Xs[r][c] = (gr < n) ? X[(size_t)gr * FDIM + c] : 0.0f;
    }
    __syncthreads();
    const int j = t & 63;
    const int ng = t >> 6;
    float acc[16];
    #pragma unroll
    for (int r = 0; r < 16; r++) acc[r] = 0.0f;
    for (int k = 0; k < 64; k++) {
        float w = Ws[k][j];
        #pragma unroll
        for (int r = 0; r < 16; r++)
            acc[r] += Xs[ng * 16 + r][k] * w;
    }
    #pragma unroll
    for (int r = 0; r < 16; r++) {
        int gr = row0 + ng * 16 + r;
        if (gr < n) {
            float dv = rsqrtf((float)cnt[gr] + 1.0f);
            Hout[(size_t)gr * FDIM + j] = __float2bfloat16(acc[r] * dv);
        }
    }
}

// ---------- layers 2/3 GEMM: Hs = bf16( rsqrt(deg+1) * (Z_bf16 @ W) ) ----------
__global__ __launch_bounds__(256) void gemm_bf16_kernel(const __hip_bfloat16* __restrict__ Z,
                                                        const float* __restrict__ W,
                                                        const int* __restrict__ cnt,
                                                        __hip_bfloat16* __restrict__ Hout, int n) {
    __shared__ float Ws[64][64];
    __shared__ float Xs[64][64];
    const int t = threadIdx.x;
    const int row0 = blockIdx.x * 64;
    const __hip_bfloat162* __restrict__ Z2 = (const __hip_bfloat162*)Z;
    #pragma unroll
    for (int i = t; i < 4096; i += 256) Ws[i >> 6][i & 63] = W[i];
    #pragma unroll
    for (int i = t; i < 2048; i += 256) {          // 2048 bf16x2 pairs per tile
        int r = i >> 5, c2 = i & 31;               // row, pair index
        int gr = row0 + r;
        float2 v = {0.f, 0.f};
        if (gr < n) {
            __hip_bfloat162 b = Z2[(size_t)gr * 32 + c2];
            v.x = __bfloat162float(b.x);
            v.y = __bfloat162float(b.y);
        }
        Xs[r][2 * c2]     = v.x;
        Xs[r][2 * c2 + 1] = v.y;
    }
    __syncthreads();
    const int j = t & 63;
    const int ng = t >> 6;
    float acc[16];
    #pragma unroll
    for (int r = 0; r < 16; r++) acc[r] = 0.0f;
    for (int k = 0; k < 64; k++) {
        float w = Ws[k][j];
        #pragma unroll
        for (int r = 0; r < 16; r++)
            acc[r] += Xs[ng * 16 + r][k] * w;
    }
    #pragma unroll
    for (int r = 0; r < 16; r++) {
        int gr = row0 + ng * 16 + r;
        if (gr < n) {
            float dv = rsqrtf((float)cnt[gr] + 1.0f);
            Hout[(size_t)gr * FDIM + j] = __float2bfloat16(acc[r] * dv);
        }
    }
}

// ---------- shared gather: sum of pre-scaled neighbor rows (+ self) ----------
// Returns per-lane float2 of features (2*(lane&31), 2*(lane&31)+1); valid in ALL lanes.
__device__ __forceinline__ float2 gather_sum(const __hip_bfloat162* __restrict__ hs2,
                                             const int* __restrict__ adjF,
                                             int v, int deg, int cap, int lane,
                                             const int* __restrict__ erow,
                                             const int* __restrict__ ecol, int etot) {
    const int f2 = lane & 31;
    const int half = lane >> 5;
    float2 a0 = {0.f,0.f}, a1 = {0.f,0.f}, a2 = {0.f,0.f}, a3 = {0.f,0.f};
    float2 a4 = {0.f,0.f}, a5 = {0.f,0.f}, a6 = {0.f,0.f}, a7 = {0.f,0.f};

    if (half == 0) {                       // self loop once
        __hip_bfloat162 sv = hs2[v * 32 + f2];
        a0.x = __bfloat162float(sv.x);
        a0.y = __bfloat162float(sv.y);
    }

    if (deg <= cap) {
        const int* __restrict__ av = adjF + (size_t)v * cap;
        for (int base = 0; base < deg; base += 64) {
            int m = deg - base; if (m > 64) m = 64;
            int uvec = 0;
            if (lane < m) uvec = av[base + lane];
            const int pairs = m >> 1;
            int k = 0;
            for (; k + 8 <= pairs; k += 8) {
                int u0 = __shfl(uvec, 2*(k+0) + half, 64);
                int u1 = __shfl(uvec, 2*(k+1) + half, 64);
                int u2 = __shfl(uvec, 2*(k+2) + half, 64);
                int u3 = __shfl(uvec, 2*(k+3) + half, 64);
                int u4 = __shfl(uvec, 2*(k+4) + half, 64);
                int u5 = __shfl(uvec, 2*(k+5) + half, 64);
                int u6 = __shfl(uvec, 2*(k+6) + half, 64);
                int u7 = __shfl(uvec, 2*(k+7) + half, 64);
                __hip_bfloat162 b0 = hs2[u0 * 32 + f2];
                __hip_bfloat162 b1 = hs2[u1 * 32 + f2];
                __hip_bfloat162 b2 = hs2[u2 * 32 + f2];
                __hip_bfloat162 b3 = hs2[u3 * 32 + f2];
                __hip_bfloat162 b4 = hs2[u4 * 32 + f2];
                __hip_bfloat162 b5 = hs2[u5 * 32 + f2];
                __hip_bfloat162 b6 = hs2[u6 * 32 + f2];
                __hip_bfloat162 b7 = hs2[u7 * 32 + f2];
                a0.x += __bfloat162float(b0.x); a0.y += __bfloat162float(b0.y);
                a1.x += __bfloat162float(b1.x); a1.y += __bfloat162float(b1.y);
                a2.x += __bfloat162float(b2.x); a2.y += __bfloat162float(b2.y);
                a3.x += __bfloat162float(b3.x); a3.y += __bfloat162float(b3.y);
                a4.x += __bfloat162float(b4.x); a4.y += __bfloat162float(b4.y);
                a5.x += __bfloat162float(b5.x); a5.y += __bfloat162float(b5.y);
                a6.x += __bfloat162float(b6.x); a6.y += __bfloat162float(b6.y);
                a7.x += __bfloat162float(b7.x); a7.y += __bfloat162float(b7.y);
            }
            for (; k < pairs; k++) {
                int u = __shfl(uvec, 2*k + half, 64);
                __hip_bfloat162 b = hs2[u * 32 + f2];
                a0.x += __bfloat162float(b.x); a0.y += __bfloat162float(b.y);
            }
            if (m & 1) {
                int u = __shfl(uvec, m - 1, 64);
                if (half == 0) {
                    __hip_bfloat162 b = hs2[u * 32 + f2];
                    a1.x += __bfloat162float(b.x); a1.y += __bfloat162float(b.y);
                }
            }
        }
    } else {
        // deg > cap (prob ~0): wave-cooperative scan of the raw edge list
        for (int base = 0; base < etot; base += 64) {
            int m = etot - base; if (m > 64) m = 64;
            int c = -1, r = 0;
            if (lane < m) { c = ecol[base + lane]; r = erow[base + lane]; }
            unsigned long long mask = __ballot(c == v);
            while (mask) {
                int j = __ffsll((long long)mask) - 1;
                mask &= mask - 1;
                int u = __shfl(r, j, 64);
                if (half == 0) {
                    __hip_bfloat162 b = hs2[u * 32 + f2];
                    a0.x += __bfloat162float(b.x); a0.y += __bfloat162float(b.y);
                }
            }
        }
    }

    float2 tot;
    tot.x = ((a0.x + a1.x) + (a2.x + a3.x)) + ((a4.x + a5.x) + (a6.x + a7.x));
    tot.y = ((a0.y + a1.y) + (a2.y + a3.y)) + ((a4.y + a5.y) + (a6.y + a7.y));
    tot.x += __shfl_xor(tot.x, 32, 64);    // combine halves
    tot.y += __shfl_xor(tot.y, 32, 64);
    return tot;
}

// ---------- agg -> z (bias + ELU), bf16 out (layers 1,2) ----------
__global__ __launch_bounds__(256) void agg_z_kernel(const __hip_bfloat16* __restrict__ hs,
                                                    const int* __restrict__ adjF,
                                                    const int* __restrict__ cnt,
                                                    const float* __restrict__ bias,
                                                    __hip_bfloat16* __restrict__ zout,
                                                    int n, int cap,
                                                    const int* __restrict__ erow,
                                                    const int* __restrict__ ecol, int etot) {
    const int v = blockIdx.x * 4 + (threadIdx.x >> 6);
    const int lane = threadIdx.x & 63;
    if (v >= n) return;
    const int f2 = lane & 31;
    const int deg = cnt[v];
    const float dv = rsqrtf((float)deg + 1.0f);
    float2 tot = gather_sum((const __hip_bfloat162*)hs, adjF, v, deg, cap, lane,
                            erow, ecol, etot);
    if ((lane >> 5) == 0) {
        float2 bv = ((const float2*)bias)[f2];
        float rx = tot.x * dv + bv.x;
        float ry = tot.y * dv + bv.y;
        rx = (rx > 0.0f) ? rx : (__expf(rx) - 1.0f);
        ry = (ry > 0.0f) ? ry : (__expf(ry) - 1.0f);
        __hip_bfloat162 o;
        o.x = __float2bfloat16(rx);
        o.y = __float2bfloat16(ry);
        ((__hip_bfloat162*)zout)[(size_t)v * 32 + f2] = o;
    }
}

// ---------- final layer: agg + bias, fp32 out, no ELU ----------
__global__ __launch_bounds__(256) void agg_final_kernel(const __hip_bfloat16* __restrict__ hs,
                                                        const int* __restrict__ adjF,
                                                        const int* __restrict__ cnt,
                                                        const float* __restrict__ bias,
                                                        float* __restrict__ out,
                                                        int n, int cap,
                                                        const int* __restrict__ erow,
                                                        const int* __restrict__ ecol, int etot) {
    const int v = blockIdx.x * 4 + (threadIdx.x >> 6);
    const int lane = threadIdx.x & 63;
    if (v >= n) return;
    const int f2 = lane & 31;
    const int deg = cnt[v];
    const float dv = rsqrtf((float)deg + 1.0f);
    float2 tot = gather_sum((const __hip_bfloat162*)hs, adjF, v, deg, cap, lane,
                            erow, ecol, etot);
    if ((lane >> 5) == 0) {
        float2 bv = ((const float2*)bias)[f2];
        float rx = tot.x * dv + bv.x;
        float ry = tot.y * dv + bv.y;
        ((float2*)out)[(size_t)v * 32 + f2] = make_float2(rx, ry);
    }
}

// ---------- launch ----------

extern "C" void kernel_launch(void* const* d_in, const int* in_sizes, int n_in,
                              void* d_out, int out_size, void* d_ws, size_t ws_size,
                              hipStream_t stream) {
    const float* x   = (const float*)d_in[0];
    const int*   ei  = (const int*)d_in[1];
    const float* W1  = (const float*)d_in[2];
    const float* b1  = (const float*)d_in[3];
    const float* W2  = (const float*)d_in[4];
    const float* b2  = (const float*)d_in[5];
    const float* W3  = (const float*)d_in[6];
    const float* b3  = (const float*)d_in[7];

    const int N = in_sizes[0] / FDIM;      // 100000
    const int E = in_sizes[1] / 2;         // 1600000
    const int* erow = ei;                   // sources
    const int* ecol = ei + E;               // targets

    char* p = (char*)d_ws;
    __hip_bfloat16* hsA = (__hip_bfloat16*)p;  p += (size_t)N * FDIM * sizeof(__hip_bfloat16);
    __hip_bfloat16* zB  = (__hip_bfloat16*)p;  p += (size_t)N * FDIM * sizeof(__hip_bfloat16);
    int* cnt  = (int*)p;  p += (size_t)N * sizeof(int);
    int* adjF = (int*)p;

    // adjacency capacity: biggest of {64,48,32} that fits the workspace
    size_t used = (size_t)(p - (char*)d_ws);
    int cap = 64;
    while (cap > 32 && used + (size_t)N * cap * sizeof(int) > ws_size) cap -= 16;

    float* outb = (float*)d_out;

    const int TB = 256;
    const int nblkE = (E + TB - 1) / TB;
    const int nblkG = (N + 63) / 64;
    const int nblkA = (N + 3) / 4;

    hipMemsetAsync(cnt, 0, (size_t)N * sizeof(int), stream);
    build_kernel<<<nblkE, TB, 0, stream>>>(erow, ecol, cnt, adjF, E, cap);

    gemm_f32_kernel<<<nblkG, TB, 0, stream>>>(x, W1, cnt, hsA, N);
    agg_z_kernel<<<nblkA, TB, 0, stream>>>(hsA, adjF, cnt, b1, zB, N, cap, erow, ecol, E);
    gemm_bf16_kernel<<<nblkG, TB, 0, stream>>>(zB, W2, cnt, hsA, N);
    agg_z_kernel<<<nblkA, TB, 0, stream>>>(hsA, adjF, cnt, b2, zB, N, cap, erow, ecol, E);
    gemm_bf16_kernel<<<nblkG, TB, 0, stream>>>(zB, W3, cnt, hsA, N);
    agg_final_kernel<<<nblkA, TB, 0, stream>>>(hsA, adjF, cnt, b3, outb, N, cap, erow, ecol, E);
}